// Round 16
// baseline (141.385 us; speedup 1.0000x reference)
//
#include <hip/hip_runtime.h>
#include <math.h>

#define B    8
#define C    1024
#define M    8
#define HW   4096
#define EPS  1e-6f
#define GAIN 0.3f

#define TPB   512
#define NT    64         // hw tiles per batch (64 hw each)
#define GRID  (B * NT)   // 512 blocks = 2/CU co-resident (LDS-capacity guaranteed)
#define NG    32         // channel groups (g = tid>>4)
#define CPG   32         // channels per group
#define SLOTS 16         // float4 hw slots (s = tid&15)

#define FLAG_OFF 2048    // float index of barrier flag in ws

typedef float floatx4 __attribute__((ext_vector_type(4)));

// ws: [512][2] stat partials + flag
__global__ __launch_bounds__(TPB, 4) void fused(const float* __restrict__ z,
                                                const float* __restrict__ Wd,
                                                float* __restrict__ out,
                                                float* __restrict__ ws) {
    // LDS: 32 (Wl) + 32 (scr) + 2 (yzacc) + eps = ~67.8 KB -> 2 blocks/CU
    __shared__ float Wl[C][M];                          // rotated W
    __shared__ __align__(16) float4 scr[NG][4][SLOTS];  // yz exchange (2 rounds x 4 m)
    __shared__ __align__(16) float4 yzacc[M][SLOTS];    // block's reduced yz
    __shared__ float wsred[8][2];                       // per-wave stat partials
    __shared__ float sh_s[M];
    __shared__ float sh_ms[2];

    const int tid = threadIdx.x;
    const int bid = blockIdx.x;
    const int b   = bid >> 6;
    const int t   = bid & 63;
    const int g   = tid >> 4;          // 32 ch-groups; rotation splits banks
    const int s   = tid & 15;          // 16 float4 slots = 64 hw
    const int rot = g & 7;

    // W -> rotated LDS: Wl[c][(m+(c>>5))&7] = W[m][c]   (identical to r12-K1)
#pragma unroll
    for (int k = 0; k < 16; ++k) {
        int idx = k * TPB + tid;       // flat m*C + c
        int m = idx >> 10, c = idx & 1023;
        Wl[c][(m + (c >> 5)) & 7] = Wd[idx];
    }
    __syncthreads();

    const size_t zoff = ((size_t)(b * C + g * CPG)) * HW + t * 64 + s * 4;

    // ---------------- phase A: read z once -> stats + ym (r12-K1 loop) -----
    float4 ym[M];
#pragma unroll
    for (int m = 0; m < M; ++m) ym[m] = make_float4(0.f, 0.f, 0.f, 0.f);
    float su = 0.f, sq = 0.f;

#pragma unroll 8
    for (int ci = 0; ci < CPG; ++ci) {
        float4 v = *reinterpret_cast<const float4*>(z + zoff + (size_t)ci * HW);
        su += (v.x + v.y) + (v.z + v.w);
        sq += v.x * v.x + v.y * v.y + v.z * v.z + v.w * v.w;
        const float* wc = &Wl[g * CPG + ci][0];
#pragma unroll
        for (int m = 0; m < M; ++m) {          // static acc index (no scratch)
            float w = wc[(m + rot) & 7];
            ym[m].x += w * v.x; ym[m].y += w * v.y;
            ym[m].z += w * v.z; ym[m].w += w * v.w;
        }
    }

    // per-wave stats shuffle reduce
    {
        float pu = su, pq = sq;
#pragma unroll
        for (int o = 32; o > 0; o >>= 1) {
            pu += __shfl_down(pu, o);
            pq += __shfl_down(pq, o);
        }
        if ((tid & 63) == 0) {
            wsred[tid >> 6][0] = pu;
            wsred[tid >> 6][1] = pq;
        }
    }

    // cross-group yz reduce: 2 rounds of 4 m's through 32 KB scr
#pragma unroll
    for (int r = 0; r < 2; ++r) {
        __syncthreads();
#pragma unroll
        for (int mm = 0; mm < 4; ++mm) scr[g][mm][s] = ym[r * 4 + mm];
        __syncthreads();
        if (tid < 64) {
            const int mm = tid >> 4, s2 = tid & 15;
            float4 a = make_float4(0.f, 0.f, 0.f, 0.f);
#pragma unroll
            for (int g2 = 0; g2 < NG; ++g2) {
                float4 p = scr[g2][mm][s2];
                a.x += p.x; a.y += p.y; a.z += p.z; a.w += p.w;
            }
            yzacc[r * 4 + mm][s2] = a;
        }
    }

    // block stats -> ws[bid]
    if (tid < 8) {
        float pu = wsred[tid][0], pq = wsred[tid][1];
#pragma unroll
        for (int o = 4; o > 0; o >>= 1) {
            pu += __shfl_down(pu, o);
            pq += __shfl_down(pq, o);
        }
        if (tid == 0) {
            ws[bid * 2]     = pu;
            ws[bid * 2 + 1] = pq;
        }
    }

    // ---------------- manual grid barrier (512 blocks, 2/CU by capacity) ---
    if (tid == 0) {
        unsigned* flag = reinterpret_cast<unsigned*>(ws + FLAG_OFF);
        __threadfence();                       // publish stats
        __hip_atomic_fetch_add(flag, 1u, __ATOMIC_ACQ_REL, __HIP_MEMORY_SCOPE_AGENT);
        for (long it = 0; it < 2000000L; ++it) {
            if (__hip_atomic_load(flag, __ATOMIC_RELAXED,
                                  __HIP_MEMORY_SCOPE_AGENT) >= (unsigned)GRID) break;
            __builtin_amdgcn_s_sleep(16);
        }
        __threadfence();                       // acquire side
    }
    __syncthreads();

    // ---------------- finalize scalars in-block ----------------------------
    if (tid < 64) {            // mu/istd from batch b's 64 block partials
        const float* sp = ws + (size_t)(b * 64 + tid) * 2;
        float pu = sp[0], pq = sp[1];
#pragma unroll
        for (int o = 32; o > 0; o >>= 1) {
            pu += __shfl_down(pu, o);
            pq += __shfl_down(pq, o);
        }
        if (tid == 0) {
            const float invN = 1.0f / (float)(C * HW);
            float mu  = pu * invN;
            float var = pq * invN - mu * mu;
            sh_ms[0] = mu;
            sh_ms[1] = 1.0f / sqrtf(var + EPS);
        }
    } else if (tid < 128) {    // s[m] from LDS W copy
        const int m = (tid - 64) >> 3, k = (tid - 64) & 7;
        float p = 0.f;
        for (int j = 0; j < 128; ++j) {
            int c = k * 128 + j;
            p += Wl[c][(m + (c >> 5)) & 7];
        }
        p += __shfl_down(p, 4);
        p += __shfl_down(p, 2);
        p += __shfl_down(p, 1);
        if (k == 0) sh_s[m] = p;
    }
    __syncthreads();
    const float mu = sh_ms[0], istd = sh_ms[1];

    float4 y4[M];
#pragma unroll
    for (int m = 0; m < M; ++m) {
        float4 a  = yzacc[m][s];               // LDS broadcast across groups
        float off = mu * sh_s[m];
        y4[m].x = istd * (a.x - off);
        y4[m].y = istd * (a.y - off);
        y4[m].z = istd * (a.z - off);
        y4[m].w = istd * (a.w - off);
    }

    // ---------------- phase B: out = z + GAIN * W^T y (z from L3) ----------
#pragma unroll 8
    for (int ci = 0; ci < CPG; ++ci) {
        float4 v = *reinterpret_cast<const float4*>(z + zoff + (size_t)ci * HW);
        const float* wc = &Wl[g * CPG + ci][0];
        float r0 = 0.f, r1 = 0.f, r2 = 0.f, r3 = 0.f;
#pragma unroll
        for (int m = 0; m < M; ++m) {
            float w = wc[(m + rot) & 7];
            r0 += w * y4[m].x; r1 += w * y4[m].y;
            r2 += w * y4[m].z; r3 += w * y4[m].w;
        }
        floatx4 o;
        o.x = v.x + GAIN * r0; o.y = v.y + GAIN * r1;
        o.z = v.z + GAIN * r2; o.w = v.w + GAIN * r3;
        __builtin_nontemporal_store(o, reinterpret_cast<floatx4*>(out + zoff + (size_t)ci * HW));
    }
}

extern "C" void kernel_launch(void* const* d_in, const int* in_sizes, int n_in,
                              void* d_out, int out_size, void* d_ws, size_t ws_size,
                              hipStream_t stream) {
    const float* z  = (const float*)d_in[0];   // (8,1024,64,64) fp32
    const float* Wd = (const float*)d_in[1];   // (8,1024) fp32
    float* out = (float*)d_out;
    float* ws  = (float*)d_ws;

    // zero the barrier flag (capture-legal async memset; deterministic per launch)
    hipMemsetAsync((char*)d_ws + FLAG_OFF * sizeof(float), 0, sizeof(unsigned), stream);
    fused<<<dim3(GRID), dim3(TPB), 0, stream>>>(z, Wd, out, ws);
}

// Round 17
// 91.592 us; speedup vs baseline: 1.5436x; 1.5436x over previous
//
#include <hip/hip_runtime.h>
#include <math.h>

#define B    8
#define C    1024
#define M    8
#define HW   4096
#define EPS  1e-6f
#define GAIN 0.3f

#define TPB   512
#define TILE  128        // hw per block
#define NTILE 32         // HW/TILE
#define GRID  (B * NTILE)   // 256 blocks = 1/CU (co-resident by capacity)
#define NG    16         // channel groups (g = tid>>5)
#define CPG   64         // channels per group
#define SLOTS 32         // float4 hw slots (s = tid&31)

#define FLAG_OFF 2048    // float index of barrier flag in ws

typedef float floatx4 __attribute__((ext_vector_type(4)));

// ws: [256][2] stat partials + flag
// launch_bounds(512, 2): min 2 waves/EU -> VGPR cap 256. The key experiment:
// free the register allocator so phase A can hold an 8-deep load pipeline
// (r12-K1 got 116 VGPR -> 5.4 TB/s; all VGPR-64 fused kernels -> ~2.4 TB/s).
__global__ __launch_bounds__(TPB, 2) void fused(const float* __restrict__ z,
                                                const float* __restrict__ Wd,
                                                float* __restrict__ out,
                                                float* __restrict__ ws) {
    // LDS: 32 (Wl) + 32 (scr) + 2 (yzacc) + eps = ~68 KB -> 1 block/CU fine
    __shared__ float Wl[C][M];                          // rotated W
    __shared__ __align__(16) float4 scr[NG][4][SLOTS];  // yz exchange (2 rounds x 4 m)
    __shared__ __align__(16) float4 yzacc[M][SLOTS];    // block's reduced yz
    __shared__ float wsred[8][2];                       // per-wave stat partials
    __shared__ float sh_s[M];
    __shared__ float sh_ms[2];

    const int tid = threadIdx.x;
    const int bid = blockIdx.x;
    const int b   = bid >> 5;
    const int t   = bid & 31;
    const int g   = tid >> 5;          // 16 groups; halves of a wave differ by 1
    const int s   = tid & 31;          // 32 float4 slots = 128 hw

    // W -> rotated LDS: Wl[c][(m+(c>>5))&7] = W[m][c]
#pragma unroll
    for (int k = 0; k < 16; ++k) {
        int idx = k * TPB + tid;       // flat m*C + c
        int m = idx >> 10, c = idx & 1023;
        Wl[c][(m + (c >> 5)) & 7] = Wd[idx];
    }
    __syncthreads();

    const size_t zoff = ((size_t)(b * C + g * CPG)) * HW + t * TILE + s * 4;

    // ---------------- phase A: read z once -> stats + ym -------------------
    float4 ym[M];
#pragma unroll
    for (int m = 0; m < M; ++m) ym[m] = make_float4(0.f, 0.f, 0.f, 0.f);
    float su = 0.f, sq = 0.f;

#pragma unroll 8
    for (int ci = 0; ci < CPG; ++ci) {
        float4 v = *reinterpret_cast<const float4*>(z + zoff + (size_t)ci * HW);
        su += (v.x + v.y) + (v.z + v.w);
        sq += v.x * v.x + v.y * v.y + v.z * v.z + v.w * v.w;
        const int c = g * CPG + ci;
        const float* wc = &Wl[c][0];
        const int rot = (c >> 5) & 7;
#pragma unroll
        for (int m = 0; m < M; ++m) {          // static acc index (no scratch)
            float w = wc[(m + rot) & 7];
            ym[m].x += w * v.x; ym[m].y += w * v.y;
            ym[m].z += w * v.z; ym[m].w += w * v.w;
        }
    }

    // per-wave stats shuffle reduce
    {
        float pu = su, pq = sq;
#pragma unroll
        for (int o = 32; o > 0; o >>= 1) {
            pu += __shfl_down(pu, o);
            pq += __shfl_down(pq, o);
        }
        if ((tid & 63) == 0) {
            wsred[tid >> 6][0] = pu;
            wsred[tid >> 6][1] = pq;
        }
    }

    // cross-group yz reduce: 2 rounds of 4 m's through 32 KB scr
#pragma unroll
    for (int r = 0; r < 2; ++r) {
        __syncthreads();
#pragma unroll
        for (int mm = 0; mm < 4; ++mm) scr[g][mm][s] = ym[r * 4 + mm];
        __syncthreads();
        if (tid < 128) {
            const int mm = tid >> 5, s2 = tid & 31;
            float4 a = make_float4(0.f, 0.f, 0.f, 0.f);
#pragma unroll
            for (int g2 = 0; g2 < NG; ++g2) {
                float4 p = scr[g2][mm][s2];
                a.x += p.x; a.y += p.y; a.z += p.z; a.w += p.w;
            }
            yzacc[r * 4 + mm][s2] = a;
        }
    }

    // block stats -> ws[bid]
    if (tid < 8) {
        float pu = wsred[tid][0], pq = wsred[tid][1];
#pragma unroll
        for (int o = 4; o > 0; o >>= 1) {
            pu += __shfl_down(pu, o);
            pq += __shfl_down(pq, o);
        }
        if (tid == 0) {
            ws[bid * 2]     = pu;
            ws[bid * 2 + 1] = pq;
        }
    }

    // ---------------- manual grid barrier (256 blocks, 1/CU) ---------------
    if (tid == 0) {
        unsigned* flag = reinterpret_cast<unsigned*>(ws + FLAG_OFF);
        __threadfence();                       // publish stats
        __hip_atomic_fetch_add(flag, 1u, __ATOMIC_ACQ_REL, __HIP_MEMORY_SCOPE_AGENT);
        for (long it = 0; it < 2000000L; ++it) {
            if (__hip_atomic_load(flag, __ATOMIC_RELAXED,
                                  __HIP_MEMORY_SCOPE_AGENT) >= (unsigned)GRID) break;
            __builtin_amdgcn_s_sleep(16);
        }
        __threadfence();                       // acquire side
    }
    __syncthreads();

    // ---------------- finalize scalars in-block ----------------------------
    if (tid < 64) {            // mu/istd from batch b's 32 block partials
        float pu = 0.f, pq = 0.f;
        if (tid < 32) {
            pu = ws[(b * 32 + tid) * 2];
            pq = ws[(b * 32 + tid) * 2 + 1];
        }
#pragma unroll
        for (int o = 16; o > 0; o >>= 1) {
            pu += __shfl_down(pu, o);
            pq += __shfl_down(pq, o);
        }
        if (tid == 0) {
            const float invN = 1.0f / (float)(C * HW);
            float mu  = pu * invN;
            float var = pq * invN - mu * mu;
            sh_ms[0] = mu;
            sh_ms[1] = 1.0f / sqrtf(var + EPS);
        }
    } else if (tid < 128) {    // s[m] from LDS W copy
        const int m = (tid - 64) >> 3, k = (tid - 64) & 7;
        float p = 0.f;
        for (int j = 0; j < 128; ++j) {
            int c = k * 128 + j;
            p += Wl[c][(m + (c >> 5)) & 7];
        }
        p += __shfl_down(p, 4);
        p += __shfl_down(p, 2);
        p += __shfl_down(p, 1);
        if (k == 0) sh_s[m] = p;
    }
    __syncthreads();
    const float mu = sh_ms[0], istd = sh_ms[1];

    float4 y4[M];
#pragma unroll
    for (int m = 0; m < M; ++m) {
        float4 a  = yzacc[m][s];               // LDS broadcast across groups
        float off = mu * sh_s[m];
        y4[m].x = istd * (a.x - off);
        y4[m].y = istd * (a.y - off);
        y4[m].z = istd * (a.z - off);
        y4[m].w = istd * (a.w - off);
    }

    // ---------------- phase B: out = z + GAIN * W^T y (z from L3) ----------
#pragma unroll 8
    for (int ci = 0; ci < CPG; ++ci) {
        float4 v = *reinterpret_cast<const float4*>(z + zoff + (size_t)ci * HW);
        const int c = g * CPG + ci;
        const float* wc = &Wl[c][0];
        const int rot = (c >> 5) & 7;
        float r0 = 0.f, r1 = 0.f, r2 = 0.f, r3 = 0.f;
#pragma unroll
        for (int m = 0; m < M; ++m) {
            float w = wc[(m + rot) & 7];
            r0 += w * y4[m].x; r1 += w * y4[m].y;
            r2 += w * y4[m].z; r3 += w * y4[m].w;
        }
        floatx4 o;
        o.x = v.x + GAIN * r0; o.y = v.y + GAIN * r1;
        o.z = v.z + GAIN * r2; o.w = v.w + GAIN * r3;
        __builtin_nontemporal_store(o, reinterpret_cast<floatx4*>(out + zoff + (size_t)ci * HW));
    }
}

extern "C" void kernel_launch(void* const* d_in, const int* in_sizes, int n_in,
                              void* d_out, int out_size, void* d_ws, size_t ws_size,
                              hipStream_t stream) {
    const float* z  = (const float*)d_in[0];   // (8,1024,64,64) fp32
    const float* Wd = (const float*)d_in[1];   // (8,1024) fp32
    float* out = (float*)d_out;
    float* ws  = (float*)d_ws;

    // zero the barrier flag (capture-legal async memset; deterministic per launch)
    hipMemsetAsync((char*)d_ws + FLAG_OFF * sizeof(float), 0, sizeof(unsigned), stream);
    fused<<<dim3(GRID), dim3(TPB), 0, stream>>>(z, Wd, out, ws);
}

// Round 18
// 70.959 us; speedup vs baseline: 1.9925x; 1.2908x over previous
//
#include <hip/hip_runtime.h>
#include <math.h>

#define B    8
#define C    1024
#define M    8
#define HW   4096
#define EPS  1e-6f
#define GAIN 0.3f

typedef float floatx4 __attribute__((ext_vector_type(4)));

// ws layout (float offsets)
#define OFF_YZW   0                          // [B][M][HW] fully-reduced unnormalized yz
#define OFF_STATP (OFF_YZW + B*M*HW)         // [512][2]
#define OFF_S     (OFF_STATP + 512*2)        // [M]

// ---------------- K1: full-C blocks -> stats partials + reduced yz ---------
// grid 512 = B*64 hw-tiles (64 hw each), TPB 512, 2 blocks/CU (16 waves/CU).
// threads: g = tid>>4 (32 ch-groups x 32 ch), s = tid&15 (16 float4 hw slots).
__global__ __launch_bounds__(512, 4) void k1_stats_yz(const float* __restrict__ z,
                                                      const float* __restrict__ Wd,
                                                      float* __restrict__ ws) {
    // W transposed + rotated: Wl[c][(m + (c>>5)) & 7] = W[m][c].
    // Read at (c, m): 4 groups in a wave -> 4 distinct banks (conflict-free).
    __shared__ float Wl[C][M];                        // 32 KB
    __shared__ __align__(16) float4 scr[32][M][16];   // 16 KB cross-group yz
    __shared__ float sred[1024];                      // 4 KB stats tree

    const int tid = threadIdx.x;
    const int bid = blockIdx.x;
    const int b   = bid >> 6;
    const int t   = bid & 63;
    const int g   = tid >> 4;
    const int s   = tid & 15;

    // coalesced W read, transposed-rotated LDS write
#pragma unroll
    for (int k = 0; k < 16; ++k) {
        int idx = k * 512 + tid;           // flat m*C + c
        int m = idx >> 10, c = idx & 1023;
        Wl[c][(m + (c >> 5)) & 7] = Wd[idx];
    }
    __syncthreads();

    float4 ym[M];
#pragma unroll
    for (int m = 0; m < M; ++m) ym[m] = make_float4(0.f, 0.f, 0.f, 0.f);
    float su = 0.f, sq = 0.f;

    const size_t zoff = ((size_t)(b * C + g * 32)) * HW + t * 64 + s * 4;
#pragma unroll 8
    for (int ci = 0; ci < 32; ++ci) {
        float4 v = *reinterpret_cast<const float4*>(z + zoff + (size_t)ci * HW);
        su += (v.x + v.y) + (v.z + v.w);
        sq += v.x * v.x + v.y * v.y + v.z * v.z + v.w * v.w;
        const int c = g * 32 + ci;
        const float* wc = &Wl[c][0];
        const int rot = (c >> 5) & 7;      // == g&7 here, runtime LDS offset is fine
#pragma unroll
        for (int m = 0; m < M; ++m) {      // ym index STATIC (no scratch)
            float w = wc[(m + rot) & 7];
            ym[m].x += w * v.x; ym[m].y += w * v.y;
            ym[m].z += w * v.z; ym[m].w += w * v.w;
        }
    }

#pragma unroll
    for (int m = 0; m < M; ++m) scr[g][m][s] = ym[m];
    sred[tid]       = su;
    sred[512 + tid] = sq;
    __syncthreads();

    // cross-group yz reduce: 128 threads, (m, slot) each sums 32 groups
    if (tid < 128) {
        const int m2 = tid >> 4, s2 = tid & 15;
        float4 a = make_float4(0.f, 0.f, 0.f, 0.f);
#pragma unroll
        for (int g2 = 0; g2 < 32; ++g2) {
            float4 p = scr[g2][m2][s2];
            a.x += p.x; a.y += p.y; a.z += p.z; a.w += p.w;
        }
        *reinterpret_cast<float4*>(ws + OFF_YZW +
            ((size_t)(b * M + m2)) * HW + t * 64 + s2 * 4) = a;
    }
    // block 0: s[m] = sum_c W[m,c] from LDS copy
    if (bid == 0 && tid < 64) {
        const int m = tid >> 3, k = tid & 7;
        float p = 0.f;
        for (int j = 0; j < 128; ++j) {
            int c = k * 128 + j;
            p += Wl[c][(m + (c >> 5)) & 7];
        }
        p += __shfl_down(p, 4);
        p += __shfl_down(p, 2);
        p += __shfl_down(p, 1);
        if (k == 0) ws[OFF_S + m] = p;
    }
    // stats tree -> statp[bid]
    for (int r = 256; r > 0; r >>= 1) {
        if (tid < r) {
            sred[tid]       += sred[tid + r];
            sred[512 + tid] += sred[512 + tid + r];
        }
        __syncthreads();
    }
    if (tid == 0) {
        ws[OFF_STATP + bid * 2]     = sred[0];
        ws[OFF_STATP + bid * 2 + 1] = sred[512];
    }
}

// ---------------- K3: finalize scalars in-block, out = z + GAIN*W^T y ------
// grid 1024 (reversed order), TPB 256, 4 blocks/CU (16 waves/CU).
__global__ __launch_bounds__(256, 4) void k3_apply(const float* __restrict__ z,
                                                   const float* __restrict__ Wd,
                                                   const float* __restrict__ ws,
                                                   float* __restrict__ out) {
    __shared__ float sh[2];
    const int tid  = threadIdx.x;
    const int rbid = 1023 - blockIdx.x;    // reverse: touch K1's freshest z first
    const int nc   = rbid & 15;
    const int t    = (rbid >> 4) & 7;
    const int b    = rbid >> 7;
    const int h    = tid >> 7;             // wave-uniform (waves 0,1 -> 0; 2,3 -> 1)
    const int sl   = tid & 127;
    const int c0   = nc * 64 + h * 32;
    const int hw   = t * 512 + sl * 4;

    // wave 0: mu/istd from 64 stat partials of batch b
    if (tid < 64) {
        const float* sp = ws + OFF_STATP + (size_t)(b * 64 + tid) * 2;
        float su = sp[0], sq = sp[1];
#pragma unroll
        for (int o = 32; o > 0; o >>= 1) {
            su += __shfl_down(su, o);
            sq += __shfl_down(sq, o);
        }
        if (tid == 0) {
            const float invN = 1.0f / (float)(C * HW);
            float mu  = su * invN;
            float var = sq * invN - mu * mu;
            sh[0] = mu;
            sh[1] = 1.0f / sqrtf(var + EPS);
        }
    }
    // overlap: scalar s[m] + raw yz loads while wave 0 reduces
    float smv[M];
#pragma unroll
    for (int m = 0; m < M; ++m) smv[m] = ws[OFF_S + m];   // uniform -> s_load
    float4 a4[M];
    const float* yp = ws + OFF_YZW + (size_t)b * M * HW + hw;
#pragma unroll
    for (int m = 0; m < M; ++m)
        a4[m] = *reinterpret_cast<const float4*>(yp + (size_t)m * HW);
    __syncthreads();
    const float mu = sh[0], istd = sh[1];

    float4 y4[M];
#pragma unroll
    for (int m = 0; m < M; ++m) {
        float off = mu * smv[m];
        y4[m].x = istd * (a4[m].x - off);
        y4[m].y = istd * (a4[m].y - off);
        y4[m].z = istd * (a4[m].z - off);
        y4[m].w = istd * (a4[m].w - off);
    }

    const float* zp = z + ((size_t)(b * C + c0)) * HW + hw;
    float* op = out + ((size_t)(b * C + c0)) * HW + hw;
#pragma unroll 8
    for (int ci = 0; ci < 32; ++ci) {
        float4 v = *reinterpret_cast<const float4*>(zp + (size_t)ci * HW);
        const int c = c0 + ci;
        float r0 = 0.f, r1 = 0.f, r2 = 0.f, r3 = 0.f;
#pragma unroll
        for (int m = 0; m < M; ++m) {
            float w = Wd[m * C + c];           // wave-uniform -> s_load
            r0 += w * y4[m].x; r1 += w * y4[m].y;
            r2 += w * y4[m].z; r3 += w * y4[m].w;
        }
        floatx4 o;
        o.x = v.x + GAIN * r0; o.y = v.y + GAIN * r1;
        o.z = v.z + GAIN * r2; o.w = v.w + GAIN * r3;
        __builtin_nontemporal_store(o, reinterpret_cast<floatx4*>(op + (size_t)ci * HW));
    }
}

extern "C" void kernel_launch(void* const* d_in, const int* in_sizes, int n_in,
                              void* d_out, int out_size, void* d_ws, size_t ws_size,
                              hipStream_t stream) {
    const float* z  = (const float*)d_in[0];   // (8,1024,64,64) fp32
    const float* Wd = (const float*)d_in[1];   // (8,1024) fp32
    float* out = (float*)d_out;
    float* ws  = (float*)d_ws;                 // ~1.05 MB

    k1_stats_yz<<<dim3(512), dim3(512), 0, stream>>>(z, Wd, ws);
    k3_apply<<<dim3(1024), dim3(256), 0, stream>>>(z, Wd, ws, out);
}